// Round 1
// baseline (199.731 us; speedup 1.0000x reference)
//
#include <hip/hip_runtime.h>

#define BB 16
#define SS 2048
#define DD 4
#define HH 256
#define FF 512
#define NTOK (BB*SS)
#define EPSF 1e-5f

// ---------------- ws float layout ----------------
// sm   : [L][128]      small fused matrices        @ 0      (256)
// w1t  : [L][512][12]  {w1col[4], w2row[4], b1, pad3}  @ 256 (12288)
// feat : [NTOK][12]    {P[4], VT[4], R, C, pad2}   @ 12544  (393216)
// X0   : [NTOK][4]                                 @ 405760 (131072)
// X1   : [NTOK][4]                                 @ 536832 (131072)
// part : [NTOK][4][5]  per-keyblock partials       @ 667904 (655360)
// total 1323264 floats = 5.3 MB

__device__ __forceinline__ float wred64(float v) {
#pragma unroll
  for (int m = 32; m > 0; m >>= 1) v += __shfl_xor(v, m, 64);
  return v;
}

// smallmat layout (per layer, stride 128):
// 0:M4[16] 16:Bk[16] 32:Bq[16] 48:WVO[16] 64:ak[4] 68:aq[4] 72:bvo[4] 76:ck 77:cq

__global__ __launch_bounds__(64) void prep_kernel(
    const float* __restrict__ Wq, const float* __restrict__ bq,
    const float* __restrict__ Wk, const float* __restrict__ bk,
    const float* __restrict__ Wv, const float* __restrict__ bv,
    const float* __restrict__ Wo, const float* __restrict__ bw,
    const float* __restrict__ W1, const float* __restrict__ b1,
    const float* __restrict__ W2,
    float* __restrict__ sm, float* __restrict__ w1t)
{
  const int i = blockIdx.x;       // layer
  const int lane = threadIdx.x;   // 0..63
  float m4[4][4] = {{0}}, gkk[4][4] = {{0}}, gqq[4][4] = {{0}}, wvo[4][4] = {{0}};
  float akk[4] = {0}, aqq[4] = {0}, bvo[4] = {0};
  float ck1 = 0.f, ck2 = 0.f, cq2 = 0.f;

  for (int h = lane; h < HH; h += 64) {
    float vq[4], vk[4], vv[4], wo4[4];
#pragma unroll
    for (int a = 0; a < 4; ++a) {
      vq[a] = Wq[(i*DD + a)*HH + h];
      vk[a] = Wk[(i*DD + a)*HH + h];
      vv[a] = Wv[(i*DD + a)*HH + h];
      wo4[a] = Wo[(i*HH + h)*DD + a];
    }
    const float bqh = bq[i*HH + h], bkh = bk[i*HH + h], bvh = bv[i*HH + h];
#pragma unroll
    for (int a = 0; a < 4; ++a) {
#pragma unroll
      for (int c = 0; c < 4; ++c) {
        m4[a][c]  = fmaf(vq[a], vk[c], m4[a][c]);
        gkk[a][c] = fmaf(vk[a], vk[c], gkk[a][c]);
        gqq[a][c] = fmaf(vq[a], vq[c], gqq[a][c]);
        wvo[a][c] = fmaf(vv[a], wo4[c], wvo[a][c]);
      }
      akk[a] = fmaf(vk[a], bqh - bkh, akk[a]);
      aqq[a] = fmaf(vq[a], bkh - bqh, aqq[a]);
      bvo[a] = fmaf(bvh, wo4[a], bvo[a]);
    }
    ck1 = fmaf(bqh, bkh, ck1);
    ck2 = fmaf(bkh, bkh, ck2);
    cq2 = fmaf(bqh, bqh, cq2);
  }
#pragma unroll
  for (int a = 0; a < 4; ++a) {
#pragma unroll
    for (int c = 0; c < 4; ++c) {
      m4[a][c]  = wred64(m4[a][c]);
      gkk[a][c] = wred64(gkk[a][c]);
      gqq[a][c] = wred64(gqq[a][c]);
      wvo[a][c] = wred64(wvo[a][c]);
    }
    akk[a] = wred64(akk[a]);
    aqq[a] = wred64(aqq[a]);
    bvo[a] = wred64(bvo[a]);
  }
  ck1 = wred64(ck1); ck2 = wred64(ck2); cq2 = wred64(cq2);

  if (lane == 0) {
    const float bwv = bw[i];
    const float bw2 = bwv * bwv;
    float* s = sm + i*128;
#pragma unroll
    for (int a = 0; a < 4; ++a) {
#pragma unroll
      for (int c = 0; c < 4; ++c) {
        s[a*4+c]      = bw2 * m4[a][c];
        s[16 + a*4+c] = -0.5f * bw2 * gkk[a][c];
        s[32 + a*4+c] = -0.5f * bw2 * gqq[a][c];
        s[48 + a*4+c] = wvo[a][c];
      }
      s[64+a] = bw2 * akk[a];
      s[68+a] = bw2 * aqq[a];
      s[72+a] = bvo[a];
    }
    s[76] = bw2 * (ck1 - 0.5f * ck2);
    s[77] = -0.5f * bw2 * cq2;
  }
  // FFN weight repack: w1t[f] = {W1[:,f], W2[f,:], b1[f], pad}
  for (int f = lane; f < FF; f += 64) {
    float* rec = w1t + (i*FF + f)*12;
#pragma unroll
    for (int c = 0; c < 4; ++c) rec[c]   = W1[(i*DD + c)*FF + f];
#pragma unroll
    for (int c = 0; c < 4; ++c) rec[4+c] = W2[(i*FF + f)*DD + c];
    rec[8] = b1[i*FF + f];
    rec[9] = 0.f; rec[10] = 0.f; rec[11] = 0.f;
  }
}

__device__ __forceinline__ void compute_feat(const float x[4], const float* __restrict__ s,
                                             float* __restrict__ featrec)
{
  float P[4], VT[4], tk[4], tq[4];
#pragma unroll
  for (int a = 0; a < 4; ++a) {
    P[a]  = fmaf(s[a*4+3], x[3], fmaf(s[a*4+2], x[2], fmaf(s[a*4+1], x[1], s[a*4+0]*x[0])));
    tk[a] = fmaf(s[16+a*4+3], x[3], fmaf(s[16+a*4+2], x[2], fmaf(s[16+a*4+1], x[1], s[16+a*4+0]*x[0])));
    tq[a] = fmaf(s[32+a*4+3], x[3], fmaf(s[32+a*4+2], x[2], fmaf(s[32+a*4+1], x[1], s[32+a*4+0]*x[0])));
    VT[a] = s[72+a] + fmaf(s[48+3*4+a], x[3], fmaf(s[48+2*4+a], x[2], fmaf(s[48+1*4+a], x[1], s[48+0*4+a]*x[0])));
  }
  float R = s[76], C = s[77];
#pragma unroll
  for (int a = 0; a < 4; ++a) {
    R = fmaf(tk[a] + s[64+a], x[a], R);
    C = fmaf(tq[a] + s[68+a], x[a], C);
  }
  float4* fp = (float4*)featrec;
  fp[0] = make_float4(P[0], P[1], P[2], P[3]);
  fp[1] = make_float4(VT[0], VT[1], VT[2], VT[3]);
  fp[2] = make_float4(R, C, 0.f, 0.f);
}

__global__ __launch_bounds__(64) void f0_kernel(
    const float* __restrict__ KEY, const float* __restrict__ VALUE,
    const float* __restrict__ sm, float* __restrict__ X0, float* __restrict__ feat)
{
  const int gq = blockIdx.x*64 + threadIdx.x;
  float x[4];
  x[0] = KEY[gq*3 + 0];
  x[1] = KEY[gq*3 + 1];
  x[2] = KEY[gq*3 + 2];
  x[3] = VALUE[gq];
  *(float4*)(X0 + gq*4) = make_float4(x[0], x[1], x[2], x[3]);
  float fr[12];
  compute_feat(x, sm, fr);
  float4* fp = (float4*)(feat + (size_t)gq*12);
  fp[0] = ((float4*)fr)[0]; fp[1] = ((float4*)fr)[1]; fp[2] = ((float4*)fr)[2];
}

// attention partial: block = 4 waves; each wave: same 256 queries (4/lane),
// its own 128-key subchunk of the block's 512-key chunk. logits broadcast from LDS.
__global__ __launch_bounds__(256) void attn_kernel(
    const float* __restrict__ feat, const float* __restrict__ X,
    float* __restrict__ part)
{
  __shared__ float smem[6144];   // 24 KB: key features [512][12], reused for reduction
  const int bid = blockIdx.x;
  const int qg = bid >> 2, kb = bid & 3;
  const int b = qg >> 3;
  const int qbase = (b << 11) + (qg & 7)*256;
  const int kbase = (b << 11) + kb*512;
  const int tid = threadIdx.x;
  const int lane = tid & 63, wave = tid >> 6;

  {
    const float4* src = (const float4*)(feat + (size_t)kbase*12);
    float4* dst = (float4*)smem;
    for (int t = tid; t < 1536; t += 256) dst[t] = src[t];
  }

  float xq[4][4], Cq[4], acc[4][5];
#pragma unroll
  for (int j = 0; j < 4; ++j) {
    const int gq = qbase + j*64 + lane;
    const float4 xv = *(const float4*)(X + gq*4);
    xq[j][0] = xv.x; xq[j][1] = xv.y; xq[j][2] = xv.z; xq[j][3] = xv.w;
    Cq[j] = feat[(size_t)gq*12 + 9];
#pragma unroll
    for (int c = 0; c < 5; ++c) acc[j][c] = 0.f;
  }
  __syncthreads();

  const float* kf = smem + wave*128*12;
#pragma unroll 2
  for (int k = 0; k < 128; ++k) {
    const float* kp = kf + k*12;
    const float4 P  = *(const float4*)kp;
    const float4 VT = *(const float4*)(kp + 4);
    const float R = kp[8];
#pragma unroll
    for (int j = 0; j < 4; ++j) {
      float l = fmaf(xq[j][3], P.w, fmaf(xq[j][2], P.z,
                fmaf(xq[j][1], P.y, fmaf(xq[j][0], P.x, R + Cq[j]))));
      const float e = __expf(l);
      acc[j][0] = fmaf(e, VT.x, acc[j][0]);
      acc[j][1] = fmaf(e, VT.y, acc[j][1]);
      acc[j][2] = fmaf(e, VT.z, acc[j][2]);
      acc[j][3] = fmaf(e, VT.w, acc[j][3]);
      acc[j][4] += e;
    }
  }
  __syncthreads();          // all waves done reading key features
  float* red = smem;        // [4][256][5]
#pragma unroll
  for (int j = 0; j < 4; ++j) {
    float* rr = red + (wave*256 + j*64 + lane)*5;
#pragma unroll
    for (int c = 0; c < 5; ++c) rr[c] = acc[j][c];
  }
  __syncthreads();
  {
    float s[5];
#pragma unroll
    for (int c = 0; c < 5; ++c)
      s[c] = red[(0*256 + tid)*5 + c] + red[(1*256 + tid)*5 + c]
           + red[(2*256 + tid)*5 + c] + red[(3*256 + tid)*5 + c];
    const int gq = qbase + tid;
    float* pp = part + (size_t)gq*20 + kb*5;
#pragma unroll
    for (int c = 0; c < 5; ++c) pp[c] = s[c];
  }
}

__device__ __forceinline__ void ln4(const float t[4], const float* __restrict__ g,
                                    const float* __restrict__ b, float r[4])
{
  const float m = 0.25f*(t[0]+t[1]+t[2]+t[3]);
  const float d0 = t[0]-m, d1 = t[1]-m, d2 = t[2]-m, d3 = t[3]-m;
  const float v = 0.25f*(d0*d0 + d1*d1 + d2*d2 + d3*d3);
  const float sc = rsqrtf(v + EPSF);
  r[0] = fmaf(d0*sc, g[0], b[0]);
  r[1] = fmaf(d1*sc, g[1], b[1]);
  r[2] = fmaf(d2*sc, g[2], b[2]);
  r[3] = fmaf(d3*sc, g[3], b[3]);
}

// combine: block = 512 thr = 64 tokens x 8 F-chunks
__global__ __launch_bounds__(512) void combine_kernel(
    const float* __restrict__ part, const float* __restrict__ Xin,
    const float* __restrict__ w1t,
    const float* __restrict__ bo, const float* __restrict__ g1, const float* __restrict__ be1,
    const float* __restrict__ b2v, const float* __restrict__ g2, const float* __restrict__ be2,
    const float* __restrict__ smn,
    float* __restrict__ Xout, float* __restrict__ feat,
    const float* __restrict__ Wfc, const float* __restrict__ bfc,
    float* __restrict__ outp, int last)
{
  const int tok = threadIdx.x & 63, fc = threadIdx.x >> 6;
  const int gq = blockIdx.x*64 + tok;
  __shared__ float ress[64][4];
  __shared__ float redb[8][64][4];

  if (fc == 0) {
    const float* pp = part + (size_t)gq*20;
    float acc[5] = {0,0,0,0,0};
#pragma unroll
    for (int kb = 0; kb < 4; ++kb)
#pragma unroll
      for (int c = 0; c < 5; ++c) acc[c] += pp[kb*5 + c];
    const float inv = 1.0f / acc[4];
    const float4 xv = *(const float4*)(Xin + gq*4);
    float t[4];
    t[0] = xv.x + fmaf(acc[0], inv, bo[0]);
    t[1] = xv.y + fmaf(acc[1], inv, bo[1]);
    t[2] = xv.z + fmaf(acc[2], inv, bo[2]);
    t[3] = xv.w + fmaf(acc[3], inv, bo[3]);
    float r[4];
    ln4(t, g1, be1, r);
    ress[tok][0] = r[0]; ress[tok][1] = r[1]; ress[tok][2] = r[2]; ress[tok][3] = r[3];
  }
  __syncthreads();
  const float r0 = ress[tok][0], r1 = ress[tok][1], r2 = ress[tok][2], r3 = ress[tok][3];
  float fa[4] = {0,0,0,0};
  const float* wt = w1t + (size_t)fc*64*12;
#pragma unroll 4
  for (int f = 0; f < 64; ++f) {
    const float* rec = wt + f*12;
    const float4 w1r = *(const float4*)rec;
    const float4 w2r = *(const float4*)(rec + 4);
    const float b1f = rec[8];
    float h = fmaf(r3, w1r.w, fmaf(r2, w1r.z, fmaf(r1, w1r.y, fmaf(r0, w1r.x, b1f))));
    h = fmaxf(h, 0.f);
    fa[0] = fmaf(h, w2r.x, fa[0]);
    fa[1] = fmaf(h, w2r.y, fa[1]);
    fa[2] = fmaf(h, w2r.z, fa[2]);
    fa[3] = fmaf(h, w2r.w, fa[3]);
  }
  redb[fc][tok][0] = fa[0]; redb[fc][tok][1] = fa[1];
  redb[fc][tok][2] = fa[2]; redb[fc][tok][3] = fa[3];
  __syncthreads();
  if (fc == 0) {
    float ff[4];
#pragma unroll
    for (int c = 0; c < 4; ++c) {
      float s = b2v[c];
#pragma unroll
      for (int k = 0; k < 8; ++k) s += redb[k][tok][c];
      ff[c] = s;
    }
    float t2[4];
#pragma unroll
    for (int c = 0; c < 4; ++c) t2[c] = ress[tok][c] + ff[c];
    float y[4];
    ln4(t2, g2, be2, y);
    if (last) {
      outp[gq] = fmaf(y[3], Wfc[3], fmaf(y[2], Wfc[2], fmaf(y[1], Wfc[1], fmaf(y[0], Wfc[0], bfc[0]))));
    } else {
      *(float4*)(Xout + gq*4) = make_float4(y[0], y[1], y[2], y[3]);
      float fr[12];
      compute_feat(y, smn, fr);
      float4* fp = (float4*)(feat + (size_t)gq*12);
      fp[0] = ((float4*)fr)[0]; fp[1] = ((float4*)fr)[1]; fp[2] = ((float4*)fr)[2];
    }
  }
}

extern "C" void kernel_launch(void* const* d_in, const int* in_sizes, int n_in,
                              void* d_out, int out_size, void* d_ws, size_t ws_size,
                              hipStream_t stream)
{
  const float* KEY   = (const float*)d_in[0];
  const float* VALUE = (const float*)d_in[1];
  const float* Wq  = (const float*)d_in[2];
  const float* bq  = (const float*)d_in[3];
  const float* Wk  = (const float*)d_in[4];
  const float* bk  = (const float*)d_in[5];
  const float* Wv  = (const float*)d_in[6];
  const float* bv  = (const float*)d_in[7];
  const float* Wo  = (const float*)d_in[8];
  const float* bo  = (const float*)d_in[9];
  const float* bw  = (const float*)d_in[10];
  const float* g1  = (const float*)d_in[11];
  const float* be1 = (const float*)d_in[12];
  const float* W1  = (const float*)d_in[13];
  const float* b1  = (const float*)d_in[14];
  const float* W2  = (const float*)d_in[15];
  const float* b2  = (const float*)d_in[16];
  const float* g2  = (const float*)d_in[17];
  const float* be2 = (const float*)d_in[18];
  const float* Wfc = (const float*)d_in[19];
  const float* bfc = (const float*)d_in[20];
  float* out = (float*)d_out;

  float* w    = (float*)d_ws;
  float* sm   = w;             // 256
  float* w1t  = w + 256;       // 12288
  float* feat = w + 12544;     // 393216
  float* X0   = w + 405760;    // 131072
  float* X1   = w + 536832;    // 131072
  float* part = w + 667904;    // 655360

  prep_kernel<<<2, 64, 0, stream>>>(Wq, bq, Wk, bk, Wv, bv, Wo, bw, W1, b1, W2, sm, w1t);
  f0_kernel<<<NTOK/64, 64, 0, stream>>>(KEY, VALUE, sm, X0, feat);

  // layer 0
  attn_kernel<<<512, 256, 0, stream>>>(feat, X0, part);
  combine_kernel<<<NTOK/64, 512, 0, stream>>>(part, X0, w1t,
      bo, g1, be1, b2, g2, be2,
      sm + 128, X1, feat, Wfc, bfc, out, 0);

  // layer 1
  attn_kernel<<<512, 256, 0, stream>>>(feat, X1, part);
  combine_kernel<<<NTOK/64, 512, 0, stream>>>(part, X1, w1t + FF*12,
      bo + 4, g1 + 4, be1 + 4, b2 + 4, g2 + 4, be2 + 4,
      sm, X0, feat, Wfc, bfc, out, 1);
}

// Round 2
// 198.427 us; speedup vs baseline: 1.0066x; 1.0066x over previous
//
#include <hip/hip_runtime.h>

#define BB 16
#define SS 2048
#define NTOK (BB*SS)
#define FF 512
#define EPSF 1e-5f

#if __has_builtin(__builtin_amdgcn_exp2f)
#define EXP2F(x) __builtin_amdgcn_exp2f(x)
#else
#define EXP2F(x) exp2f(x)
#endif

// ---------------- ws float layout ----------------
// sm   : [L][64]       fused small mats (exp2-prescaled)   @ 0       (128)
// w1t  : [L][512][12]  {w1col[4], w2row[4], b1, pad3}      @ 128     (12288)
// feat : [NTOK][12]    {P[4], VT[4], R, pad3}              @ 12416   (393216)
// X0   : [NTOK][4]                                         @ 405632  (131072)
// X1   : [NTOK][4]                                         @ 536704  (131072)
// part : [32][NTOK][5] per-(keyblock,wave) partials        @ 667776  (5242880)
// total 5,910,656 floats = 23.6 MB

__device__ __forceinline__ float wred64(float v) {
#pragma unroll
  for (int m = 32; m > 0; m >>= 1) v += __shfl_xor(v, m, 64);
  return v;
}

// sm layout (per layer, stride 64):
// 0:M4[16] (bw2*Wq^T Wk)   16:Bk[16] (-.5 bw2 Wk^T Wk)   32:WVO[16] (Wv*Wo)
// 48:ak[4]  52:bvo[4]  56:ck      where bw2 = bw^2 * log2(e)

__global__ __launch_bounds__(64) void prep_kernel(
    const float* __restrict__ Wq, const float* __restrict__ bq,
    const float* __restrict__ Wk, const float* __restrict__ bk,
    const float* __restrict__ Wv, const float* __restrict__ bv,
    const float* __restrict__ Wo, const float* __restrict__ bw,
    const float* __restrict__ W1, const float* __restrict__ b1,
    const float* __restrict__ W2,
    float* __restrict__ sm, float* __restrict__ w1t)
{
  const int i = blockIdx.x;       // layer
  const int lane = threadIdx.x;   // 0..63
  float m4[4][4] = {{0}}, gkk[4][4] = {{0}}, wvo[4][4] = {{0}};
  float akk[4] = {0}, bvo[4] = {0};
  float ck1 = 0.f, ck2 = 0.f;

  for (int h = lane; h < 256; h += 64) {
    float vq[4], vk[4], vv[4], wo4[4];
#pragma unroll
    for (int a = 0; a < 4; ++a) {
      vq[a]  = Wq[(i*4 + a)*256 + h];
      vk[a]  = Wk[(i*4 + a)*256 + h];
      vv[a]  = Wv[(i*4 + a)*256 + h];
      wo4[a] = Wo[(i*256 + h)*4 + a];
    }
    const float bqh = bq[i*256 + h], bkh = bk[i*256 + h], bvh = bv[i*256 + h];
#pragma unroll
    for (int a = 0; a < 4; ++a) {
#pragma unroll
      for (int c = 0; c < 4; ++c) {
        m4[a][c]  = fmaf(vq[a], vk[c], m4[a][c]);
        gkk[a][c] = fmaf(vk[a], vk[c], gkk[a][c]);
        wvo[a][c] = fmaf(vv[a], wo4[c], wvo[a][c]);
      }
      akk[a] = fmaf(vk[a], bqh - bkh, akk[a]);
      bvo[a] = fmaf(bvh, wo4[a], bvo[a]);
    }
    ck1 = fmaf(bqh, bkh, ck1);
    ck2 = fmaf(bkh, bkh, ck2);
  }
#pragma unroll
  for (int a = 0; a < 4; ++a) {
#pragma unroll
    for (int c = 0; c < 4; ++c) {
      m4[a][c]  = wred64(m4[a][c]);
      gkk[a][c] = wred64(gkk[a][c]);
      wvo[a][c] = wred64(wvo[a][c]);
    }
    akk[a] = wred64(akk[a]);
    bvo[a] = wred64(bvo[a]);
  }
  ck1 = wred64(ck1); ck2 = wred64(ck2);

  if (lane == 0) {
    const float bwv = bw[i];
    const float bw2 = bwv * bwv * 1.44269504088896f;   // exp2 prescale
    float* s = sm + i*64;
#pragma unroll
    for (int a = 0; a < 4; ++a) {
#pragma unroll
      for (int c = 0; c < 4; ++c) {
        s[a*4+c]      = bw2 * m4[a][c];
        s[16 + a*4+c] = -0.5f * bw2 * gkk[a][c];
        s[32 + a*4+c] = wvo[a][c];
      }
      s[48+a] = bw2 * akk[a];
      s[52+a] = bvo[a];
    }
    s[56] = bw2 * (ck1 - 0.5f * ck2);
  }
  // FFN weight repack: w1t[f] = {W1[:,f], W2[f,:], b1[f], pad}
  for (int f = lane; f < FF; f += 64) {
    float* rec = w1t + (i*FF + f)*12;
#pragma unroll
    for (int c = 0; c < 4; ++c) rec[c]   = W1[(i*4 + c)*FF + f];
#pragma unroll
    for (int c = 0; c < 4; ++c) rec[4+c] = W2[(i*FF + f)*4 + c];
    rec[8] = b1[i*FF + f];
    rec[9] = 0.f; rec[10] = 0.f; rec[11] = 0.f;
  }
}

// feat record: {P[4], VT[4], R, pad3}; query-side constant dropped (cancels in softmax)
__device__ __forceinline__ void compute_feat(const float x[4], const float* __restrict__ s,
                                             float* __restrict__ featrec)
{
  float P[4], VT[4], tk[4];
#pragma unroll
  for (int a = 0; a < 4; ++a) {
    P[a]  = fmaf(s[a*4+3], x[3], fmaf(s[a*4+2], x[2], fmaf(s[a*4+1], x[1], s[a*4+0]*x[0])));
    tk[a] = fmaf(s[16+a*4+3], x[3], fmaf(s[16+a*4+2], x[2], fmaf(s[16+a*4+1], x[1], s[16+a*4+0]*x[0])));
    VT[a] = s[52+a] + fmaf(s[32+3*4+a], x[3], fmaf(s[32+2*4+a], x[2], fmaf(s[32+1*4+a], x[1], s[32+0*4+a]*x[0])));
  }
  float R = s[56];
#pragma unroll
  for (int a = 0; a < 4; ++a) R = fmaf(tk[a] + s[48+a], x[a], R);
  float4* fp = (float4*)featrec;
  fp[0] = make_float4(P[0], P[1], P[2], P[3]);
  fp[1] = make_float4(VT[0], VT[1], VT[2], VT[3]);
  fp[2] = make_float4(R, 0.f, 0.f, 0.f);
}

__global__ __launch_bounds__(256) void f0_kernel(
    const float* __restrict__ KEY, const float* __restrict__ VALUE,
    const float* __restrict__ sm, float* __restrict__ X0, float* __restrict__ feat)
{
  const int gq = blockIdx.x*256 + threadIdx.x;
  float x[4];
  x[0] = KEY[gq*3 + 0];
  x[1] = KEY[gq*3 + 1];
  x[2] = KEY[gq*3 + 2];
  x[3] = VALUE[gq];
  *(float4*)(X0 + (size_t)gq*4) = make_float4(x[0], x[1], x[2], x[3]);
  float fr[12];
  compute_feat(x, sm, fr);
  float4* fp = (float4*)(feat + (size_t)gq*12);
  fp[0] = ((float4*)fr)[0]; fp[1] = ((float4*)fr)[1]; fp[2] = ((float4*)fr)[2];
}

// attention partials: block covers 512 queries x 256 keys.
// 4 waves share the 512 queries (8 q/lane); each wave owns 64 of the 256 staged keys.
// Per (keyblock,wave) stripe written independently -> 32 stripes/query.
__global__ __launch_bounds__(256) void attn_kernel(
    const float* __restrict__ feat, const float* __restrict__ X,
    float* __restrict__ part)
{
  __shared__ float kbuf[256*12];    // 12 KB
  const int bid = blockIdx.x;
  const int b = bid >> 5;
  const int r = bid & 31;
  const int qg = r >> 3, kb = r & 7;
  const int qbase = (b << 11) + (qg << 9);
  const int kbase = (b << 11) + (kb << 8);
  const int tid = threadIdx.x;
  const int lane = tid & 63, wave = tid >> 6;

  {
    const float4* src = (const float4*)(feat + (size_t)kbase*12);
    float4* dst = (float4*)kbuf;
    dst[tid] = src[tid];
    dst[tid + 256] = src[tid + 256];
    dst[tid + 512] = src[tid + 512];
  }

  float xq[8][4], acc[8][5];
#pragma unroll
  for (int j = 0; j < 8; ++j) {
    const float4 xv = *(const float4*)(X + (size_t)(qbase + j*64 + lane)*4);
    xq[j][0] = xv.x; xq[j][1] = xv.y; xq[j][2] = xv.z; xq[j][3] = xv.w;
#pragma unroll
    for (int c = 0; c < 5; ++c) acc[j][c] = 0.f;
  }
  __syncthreads();

  const float* kf = kbuf + wave*64*12;
#pragma unroll 2
  for (int k = 0; k < 64; ++k) {
    const float* kp = kf + k*12;
    const float4 P  = *(const float4*)kp;
    const float4 VT = *(const float4*)(kp + 4);
    const float R = kp[8];
#pragma unroll
    for (int j = 0; j < 8; ++j) {
      float l = fmaf(xq[j][3], P.w, fmaf(xq[j][2], P.z,
                fmaf(xq[j][1], P.y, fmaf(xq[j][0], P.x, R))));
      const float e = EXP2F(l);
      acc[j][0] = fmaf(e, VT.x, acc[j][0]);
      acc[j][1] = fmaf(e, VT.y, acc[j][1]);
      acc[j][2] = fmaf(e, VT.z, acc[j][2]);
      acc[j][3] = fmaf(e, VT.w, acc[j][3]);
      acc[j][4] += e;
    }
  }

  const int stripe = (kb << 2) + wave;
  float* pb = part + (size_t)stripe * NTOK * 5;
#pragma unroll
  for (int j = 0; j < 8; ++j) {
    float* pp = pb + (size_t)(qbase + j*64 + lane)*5;
    pp[0] = acc[j][0]; pp[1] = acc[j][1]; pp[2] = acc[j][2];
    pp[3] = acc[j][3]; pp[4] = acc[j][4];
  }
}

__device__ __forceinline__ void ln4(const float t[4], const float* __restrict__ g,
                                    const float* __restrict__ b, float r[4])
{
  const float m = 0.25f*(t[0]+t[1]+t[2]+t[3]);
  const float d0 = t[0]-m, d1 = t[1]-m, d2 = t[2]-m, d3 = t[3]-m;
  const float v = 0.25f*(d0*d0 + d1*d1 + d2*d2 + d3*d3);
  const float sc = rsqrtf(v + EPSF);
  r[0] = fmaf(d0*sc, g[0], b[0]);
  r[1] = fmaf(d1*sc, g[1], b[1]);
  r[2] = fmaf(d2*sc, g[2], b[2]);
  r[3] = fmaf(d3*sc, g[3], b[3]);
}

// combine: block = 512 thr = 64 tokens x 8 F-chunks; also reduces the 32 part stripes
__global__ __launch_bounds__(512) void combine_kernel(
    const float* __restrict__ part, const float* __restrict__ Xin,
    const float* __restrict__ w1t,
    const float* __restrict__ bo, const float* __restrict__ g1, const float* __restrict__ be1,
    const float* __restrict__ b2v, const float* __restrict__ g2, const float* __restrict__ be2,
    const float* __restrict__ smn,
    float* __restrict__ Xout, float* __restrict__ feat,
    const float* __restrict__ Wfc, const float* __restrict__ bfc,
    float* __restrict__ outp, int last)
{
  const int tok = threadIdx.x & 63, fc = threadIdx.x >> 6;
  const int gq = blockIdx.x*64 + tok;
  __shared__ float redp[8][64][5];
  __shared__ float ress[64][4];
  __shared__ float redf[8][64][4];

  // stripe reduction: each fc sums 4 of the 32 stripes
  {
    float a5[5] = {0,0,0,0,0};
#pragma unroll
    for (int s = 0; s < 4; ++s) {
      const float* pp = part + ((size_t)(fc*4 + s)*NTOK + gq)*5;
#pragma unroll
      for (int c = 0; c < 5; ++c) a5[c] += pp[c];
    }
#pragma unroll
    for (int c = 0; c < 5; ++c) redp[fc][tok][c] = a5[c];
  }
  __syncthreads();

  if (fc == 0) {
    float acc[5] = {0,0,0,0,0};
#pragma unroll
    for (int k = 0; k < 8; ++k)
#pragma unroll
      for (int c = 0; c < 5; ++c) acc[c] += redp[k][tok][c];
    const float inv = 1.0f / acc[4];
    const float4 xv = *(const float4*)(Xin + (size_t)gq*4);
    float t[4];
    t[0] = xv.x + fmaf(acc[0], inv, bo[0]);
    t[1] = xv.y + fmaf(acc[1], inv, bo[1]);
    t[2] = xv.z + fmaf(acc[2], inv, bo[2]);
    t[3] = xv.w + fmaf(acc[3], inv, bo[3]);
    float r[4];
    ln4(t, g1, be1, r);
    ress[tok][0] = r[0]; ress[tok][1] = r[1]; ress[tok][2] = r[2]; ress[tok][3] = r[3];
  }
  __syncthreads();

  const float r0 = ress[tok][0], r1 = ress[tok][1], r2 = ress[tok][2], r3 = ress[tok][3];
  float fa[4] = {0,0,0,0};
  const float* wt = w1t + (size_t)fc*64*12;
#pragma unroll 4
  for (int f = 0; f < 64; ++f) {
    const float* rec = wt + f*12;
    const float4 w1r = *(const float4*)rec;
    const float4 w2r = *(const float4*)(rec + 4);
    const float b1f = rec[8];
    float h = fmaf(r3, w1r.w, fmaf(r2, w1r.z, fmaf(r1, w1r.y, fmaf(r0, w1r.x, b1f))));
    h = fmaxf(h, 0.f);
    fa[0] = fmaf(h, w2r.x, fa[0]);
    fa[1] = fmaf(h, w2r.y, fa[1]);
    fa[2] = fmaf(h, w2r.z, fa[2]);
    fa[3] = fmaf(h, w2r.w, fa[3]);
  }
  redf[fc][tok][0] = fa[0]; redf[fc][tok][1] = fa[1];
  redf[fc][tok][2] = fa[2]; redf[fc][tok][3] = fa[3];
  __syncthreads();

  if (fc == 0) {
    float t2[4];
#pragma unroll
    for (int c = 0; c < 4; ++c) {
      float s = b2v[c];
#pragma unroll
      for (int k = 0; k < 8; ++k) s += redf[k][tok][c];
      t2[c] = ress[tok][c] + s;
    }
    float y[4];
    ln4(t2, g2, be2, y);
    if (last) {
      outp[gq] = fmaf(y[3], Wfc[3], fmaf(y[2], Wfc[2], fmaf(y[1], Wfc[1], fmaf(y[0], Wfc[0], bfc[0]))));
    } else {
      *(float4*)(Xout + (size_t)gq*4) = make_float4(y[0], y[1], y[2], y[3]);
      float fr[12];
      compute_feat(y, smn, fr);
      float4* fp = (float4*)(feat + (size_t)gq*12);
      fp[0] = ((float4*)fr)[0]; fp[1] = ((float4*)fr)[1]; fp[2] = ((float4*)fr)[2];
    }
  }
}

extern "C" void kernel_launch(void* const* d_in, const int* in_sizes, int n_in,
                              void* d_out, int out_size, void* d_ws, size_t ws_size,
                              hipStream_t stream)
{
  const float* KEY   = (const float*)d_in[0];
  const float* VALUE = (const float*)d_in[1];
  const float* Wq  = (const float*)d_in[2];
  const float* bq  = (const float*)d_in[3];
  const float* Wk  = (const float*)d_in[4];
  const float* bk  = (const float*)d_in[5];
  const float* Wv  = (const float*)d_in[6];
  const float* bv  = (const float*)d_in[7];
  const float* Wo  = (const float*)d_in[8];
  const float* bo  = (const float*)d_in[9];
  const float* bw  = (const float*)d_in[10];
  const float* g1  = (const float*)d_in[11];
  const float* be1 = (const float*)d_in[12];
  const float* W1  = (const float*)d_in[13];
  const float* b1  = (const float*)d_in[14];
  const float* W2  = (const float*)d_in[15];
  const float* b2  = (const float*)d_in[16];
  const float* g2  = (const float*)d_in[17];
  const float* be2 = (const float*)d_in[18];
  const float* Wfc = (const float*)d_in[19];
  const float* bfc = (const float*)d_in[20];
  float* out = (float*)d_out;

  float* w    = (float*)d_ws;
  float* sm   = w;              // 128
  float* w1t  = w + 128;        // 12288
  float* feat = w + 12416;      // 393216
  float* X0   = w + 405632;     // 131072
  float* X1   = w + 536704;     // 131072
  float* part = w + 667776;     // 5242880

  prep_kernel<<<2, 64, 0, stream>>>(Wq, bq, Wk, bk, Wv, bv, Wo, bw, W1, b1, W2, sm, w1t);
  f0_kernel<<<128, 256, 0, stream>>>(KEY, VALUE, sm, X0, feat);

  // layer 0
  attn_kernel<<<512, 256, 0, stream>>>(feat, X0, part);
  combine_kernel<<<512, 512, 0, stream>>>(part, X0, w1t,
      bo, g1, be1, b2, g2, be2,
      sm + 64, X1, feat, Wfc, bfc, out, 0);

  // layer 1
  attn_kernel<<<512, 256, 0, stream>>>(feat, X1, part);
  combine_kernel<<<512, 512, 0, stream>>>(part, X1, w1t + FF*12,
      bo + 4, g1 + 4, be1 + 4, b2 + 4, g2 + 4, be2 + 4,
      sm, X0, feat, Wfc, bfc, out, 1);
}

// Round 3
// 191.797 us; speedup vs baseline: 1.0414x; 1.0346x over previous
//
#include <hip/hip_runtime.h>

#define BB 16
#define SS 2048
#define NTOK (BB*SS)
#define FF 512
#define EPSF 1e-5f

#if __has_builtin(__builtin_amdgcn_exp2f)
#define EXP2F(x) __builtin_amdgcn_exp2f(x)
#else
#define EXP2F(x) exp2f(x)
#endif

// ---------------- ws float layout ----------------
// sm   : [L][64]       fused small mats (exp2-prescaled)   @ 0       (128)
// w1t  : [L][512][12]  {w1col[4], w2row[4], b1, pad3}      @ 128     (12288)
// feat : [NTOK][12]    {P[4], VT[4], R, pad3}              @ 12416   (393216)
// X0   : [NTOK][4]                                         @ 405632  (131072)
// X1   : [NTOK][4]                                         @ 536704  (131072)
// part : [8][NTOK][8]  per-keyblock partials (padded to 8) @ 667776  (2097152)
// total 2,764,928 floats = 11.1 MB

__device__ __forceinline__ float wred64(float v) {
#pragma unroll
  for (int m = 32; m > 0; m >>= 1) v += __shfl_xor(v, m, 64);
  return v;
}

// sm layout (per layer, stride 64):
// 0:M4[16] (bw2*Wq^T Wk)   16:Bk[16] (-.5 bw2 Wk^T Wk)   32:WVO[16] (Wv*Wo)
// 48:ak[4]  52:bvo[4]  56:ck      where bw2 = bw^2 * log2(e)

__global__ __launch_bounds__(64) void prep_kernel(
    const float* __restrict__ Wq, const float* __restrict__ bq,
    const float* __restrict__ Wk, const float* __restrict__ bk,
    const float* __restrict__ Wv, const float* __restrict__ bv,
    const float* __restrict__ Wo, const float* __restrict__ bw,
    const float* __restrict__ W1, const float* __restrict__ b1,
    const float* __restrict__ W2,
    float* __restrict__ sm, float* __restrict__ w1t)
{
  const int i = blockIdx.x;       // layer
  const int lane = threadIdx.x;   // 0..63
  float m4[4][4] = {{0}}, gkk[4][4] = {{0}}, wvo[4][4] = {{0}};
  float akk[4] = {0}, bvo[4] = {0};
  float ck1 = 0.f, ck2 = 0.f;

  for (int h = lane; h < 256; h += 64) {
    float vq[4], vk[4], vv[4], wo4[4];
#pragma unroll
    for (int a = 0; a < 4; ++a) {
      vq[a]  = Wq[(i*4 + a)*256 + h];
      vk[a]  = Wk[(i*4 + a)*256 + h];
      vv[a]  = Wv[(i*4 + a)*256 + h];
      wo4[a] = Wo[(i*256 + h)*4 + a];
    }
    const float bqh = bq[i*256 + h], bkh = bk[i*256 + h], bvh = bv[i*256 + h];
#pragma unroll
    for (int a = 0; a < 4; ++a) {
#pragma unroll
      for (int c = 0; c < 4; ++c) {
        m4[a][c]  = fmaf(vq[a], vk[c], m4[a][c]);
        gkk[a][c] = fmaf(vk[a], vk[c], gkk[a][c]);
        wvo[a][c] = fmaf(vv[a], wo4[c], wvo[a][c]);
      }
      akk[a] = fmaf(vk[a], bqh - bkh, akk[a]);
      bvo[a] = fmaf(bvh, wo4[a], bvo[a]);
    }
    ck1 = fmaf(bqh, bkh, ck1);
    ck2 = fmaf(bkh, bkh, ck2);
  }
#pragma unroll
  for (int a = 0; a < 4; ++a) {
#pragma unroll
    for (int c = 0; c < 4; ++c) {
      m4[a][c]  = wred64(m4[a][c]);
      gkk[a][c] = wred64(gkk[a][c]);
      wvo[a][c] = wred64(wvo[a][c]);
    }
    akk[a] = wred64(akk[a]);
    bvo[a] = wred64(bvo[a]);
  }
  ck1 = wred64(ck1); ck2 = wred64(ck2);

  if (lane == 0) {
    const float bwv = bw[i];
    const float bw2 = bwv * bwv * 1.44269504088896f;   // exp2 prescale
    float* s = sm + i*64;
#pragma unroll
    for (int a = 0; a < 4; ++a) {
#pragma unroll
      for (int c = 0; c < 4; ++c) {
        s[a*4+c]      = bw2 * m4[a][c];
        s[16 + a*4+c] = -0.5f * bw2 * gkk[a][c];
        s[32 + a*4+c] = wvo[a][c];
      }
      s[48+a] = bw2 * akk[a];
      s[52+a] = bvo[a];
    }
    s[56] = bw2 * (ck1 - 0.5f * ck2);
  }
  // FFN weight repack: w1t[f] = {W1[:,f], W2[f,:], b1[f], pad}
  for (int f = lane; f < FF; f += 64) {
    float* rec = w1t + (i*FF + f)*12;
#pragma unroll
    for (int c = 0; c < 4; ++c) rec[c]   = W1[(i*4 + c)*FF + f];
#pragma unroll
    for (int c = 0; c < 4; ++c) rec[4+c] = W2[(i*FF + f)*4 + c];
    rec[8] = b1[i*FF + f];
    rec[9] = 0.f; rec[10] = 0.f; rec[11] = 0.f;
  }
}

// feat record: {P[4], VT[4], R, pad3}; query-side constant dropped (cancels in softmax)
__device__ __forceinline__ void compute_feat(const float x[4], const float* __restrict__ s,
                                             float* __restrict__ featrec)
{
  float P[4], VT[4], tk[4];
#pragma unroll
  for (int a = 0; a < 4; ++a) {
    P[a]  = fmaf(s[a*4+3], x[3], fmaf(s[a*4+2], x[2], fmaf(s[a*4+1], x[1], s[a*4+0]*x[0])));
    tk[a] = fmaf(s[16+a*4+3], x[3], fmaf(s[16+a*4+2], x[2], fmaf(s[16+a*4+1], x[1], s[16+a*4+0]*x[0])));
    VT[a] = s[52+a] + fmaf(s[32+3*4+a], x[3], fmaf(s[32+2*4+a], x[2], fmaf(s[32+1*4+a], x[1], s[32+0*4+a]*x[0])));
  }
  float R = s[56];
#pragma unroll
  for (int a = 0; a < 4; ++a) R = fmaf(tk[a] + s[48+a], x[a], R);
  float4* fp = (float4*)featrec;
  fp[0] = make_float4(P[0], P[1], P[2], P[3]);
  fp[1] = make_float4(VT[0], VT[1], VT[2], VT[3]);
  fp[2] = make_float4(R, 0.f, 0.f, 0.f);
}

__global__ __launch_bounds__(256) void f0_kernel(
    const float* __restrict__ KEY, const float* __restrict__ VALUE,
    const float* __restrict__ sm, float* __restrict__ X0, float* __restrict__ feat)
{
  const int gq = blockIdx.x*256 + threadIdx.x;
  float x[4];
  x[0] = KEY[gq*3 + 0];
  x[1] = KEY[gq*3 + 1];
  x[2] = KEY[gq*3 + 2];
  x[3] = VALUE[gq];
  *(float4*)(X0 + (size_t)gq*4) = make_float4(x[0], x[1], x[2], x[3]);
  float fr[12];
  compute_feat(x, sm, fr);
  float4* fp = (float4*)(feat + (size_t)gq*12);
  fp[0] = ((float4*)fr)[0]; fp[1] = ((float4*)fr)[1]; fp[2] = ((float4*)fr)[2];
}

// attention partials: block covers 512 queries x 256 keys.
// 4 waves share the 512 queries (8 q/lane); each wave owns 64 of the 256 staged keys.
// Cross-wave LDS reduction -> one stripe per keyblock (8 stripes total).
// LDS red layout stride 21 (gcd(21,32)=1 -> 2-way bank aliasing only, free).
__global__ __launch_bounds__(256) void attn_kernel(
    const float* __restrict__ feat, const float* __restrict__ X,
    float* __restrict__ part)
{
  __shared__ float smem[512*21];    // 43 KB; first 3072 floats double as key buffer
  const int bid = blockIdx.x;
  const int b = bid >> 5;
  const int r = bid & 31;
  const int qg = r >> 3, kb = r & 7;
  const int qbase = (b << 11) + (qg << 9);
  const int kbase = (b << 11) + (kb << 8);
  const int tid = threadIdx.x;
  const int lane = tid & 63, wave = tid >> 6;

  {
    const float4* src = (const float4*)(feat + (size_t)kbase*12);
    float4* dst = (float4*)smem;
    dst[tid] = src[tid];
    dst[tid + 256] = src[tid + 256];
    dst[tid + 512] = src[tid + 512];
  }

  float xq[8][4], acc[8][5];
#pragma unroll
  for (int j = 0; j < 8; ++j) {
    const float4 xv = *(const float4*)(X + (size_t)(qbase + j*64 + lane)*4);
    xq[j][0] = xv.x; xq[j][1] = xv.y; xq[j][2] = xv.z; xq[j][3] = xv.w;
#pragma unroll
    for (int c = 0; c < 5; ++c) acc[j][c] = 0.f;
  }
  __syncthreads();

  const float* kf = smem + wave*64*12;
#pragma unroll 2
  for (int k = 0; k < 64; ++k) {
    const float* kp = kf + k*12;
    const float4 P  = *(const float4*)kp;
    const float4 VT = *(const float4*)(kp + 4);
    const float R = kp[8];
#pragma unroll
    for (int j = 0; j < 8; ++j) {
      float l = fmaf(xq[j][3], P.w, fmaf(xq[j][2], P.z,
                fmaf(xq[j][1], P.y, fmaf(xq[j][0], P.x, R))));
      const float e = EXP2F(l);
      acc[j][0] = fmaf(e, VT.x, acc[j][0]);
      acc[j][1] = fmaf(e, VT.y, acc[j][1]);
      acc[j][2] = fmaf(e, VT.z, acc[j][2]);
      acc[j][3] = fmaf(e, VT.w, acc[j][3]);
      acc[j][4] += e;
    }
  }
  __syncthreads();     // key buffer dead; reuse LDS for cross-wave reduction
#pragma unroll
  for (int j = 0; j < 8; ++j) {
    float* rr = smem + (j*64 + lane)*21 + wave*5;
    rr[0] = acc[j][0]; rr[1] = acc[j][1]; rr[2] = acc[j][2];
    rr[3] = acc[j][3]; rr[4] = acc[j][4];
  }
  __syncthreads();
  float* pb = part + (size_t)kb * NTOK * 8;
#pragma unroll
  for (int t = 0; t < 2; ++t) {
    const int q = t*256 + tid;
    const float* rr = smem + q*21;
    float s0 = 0.f, s1 = 0.f, s2 = 0.f, s3 = 0.f, s4 = 0.f;
#pragma unroll
    for (int w = 0; w < 4; ++w) {
      s0 += rr[w*5+0]; s1 += rr[w*5+1]; s2 += rr[w*5+2];
      s3 += rr[w*5+3]; s4 += rr[w*5+4];
    }
    float* pp = pb + (size_t)(qbase + q)*8;
    *(float4*)pp = make_float4(s0, s1, s2, s3);
    pp[4] = s4;
  }
}

__device__ __forceinline__ void ln4(const float t[4], const float* __restrict__ g,
                                    const float* __restrict__ b, float r[4])
{
  const float m = 0.25f*(t[0]+t[1]+t[2]+t[3]);
  const float d0 = t[0]-m, d1 = t[1]-m, d2 = t[2]-m, d3 = t[3]-m;
  const float v = 0.25f*(d0*d0 + d1*d1 + d2*d2 + d3*d3);
  const float sc = rsqrtf(v + EPSF);
  r[0] = fmaf(d0*sc, g[0], b[0]);
  r[1] = fmaf(d1*sc, g[1], b[1]);
  r[2] = fmaf(d2*sc, g[2], b[2]);
  r[3] = fmaf(d3*sc, g[3], b[3]);
}

// combine: block = 512 thr = 64 tokens x 8 F-chunks; fc k reduces part stripe k
__global__ __launch_bounds__(512) void combine_kernel(
    const float* __restrict__ part, const float* __restrict__ Xin,
    const float* __restrict__ w1t,
    const float* __restrict__ bo, const float* __restrict__ g1, const float* __restrict__ be1,
    const float* __restrict__ b2v, const float* __restrict__ g2, const float* __restrict__ be2,
    const float* __restrict__ smn,
    float* __restrict__ Xout, float* __restrict__ feat,
    const float* __restrict__ Wfc, const float* __restrict__ bfc,
    float* __restrict__ outp, int last)
{
  const int tok = threadIdx.x & 63, fc = threadIdx.x >> 6;
  const int gq = blockIdx.x*64 + tok;
  __shared__ float redp[8][64][5];
  __shared__ float ress[64][4];
  __shared__ float redf[8][64][4];

  {
    const float* pp = part + ((size_t)fc*NTOK + gq)*8;
    const float4 v = *(const float4*)pp;
    redp[fc][tok][0] = v.x; redp[fc][tok][1] = v.y;
    redp[fc][tok][2] = v.z; redp[fc][tok][3] = v.w;
    redp[fc][tok][4] = pp[4];
  }
  __syncthreads();

  if (fc == 0) {
    float acc[5] = {0,0,0,0,0};
#pragma unroll
    for (int k = 0; k < 8; ++k)
#pragma unroll
      for (int c = 0; c < 5; ++c) acc[c] += redp[k][tok][c];
    const float inv = 1.0f / acc[4];
    const float4 xv = *(const float4*)(Xin + (size_t)gq*4);
    float t[4];
    t[0] = xv.x + fmaf(acc[0], inv, bo[0]);
    t[1] = xv.y + fmaf(acc[1], inv, bo[1]);
    t[2] = xv.z + fmaf(acc[2], inv, bo[2]);
    t[3] = xv.w + fmaf(acc[3], inv, bo[3]);
    float r[4];
    ln4(t, g1, be1, r);
    ress[tok][0] = r[0]; ress[tok][1] = r[1]; ress[tok][2] = r[2]; ress[tok][3] = r[3];
  }
  __syncthreads();

  const float r0 = ress[tok][0], r1 = ress[tok][1], r2 = ress[tok][2], r3 = ress[tok][3];
  float fa[4] = {0,0,0,0};
  const float* wt = w1t + (size_t)fc*64*12;
#pragma unroll 4
  for (int f = 0; f < 64; ++f) {
    const float* rec = wt + f*12;
    const float4 w1r = *(const float4*)rec;
    const float4 w2r = *(const float4*)(rec + 4);
    const float b1f = rec[8];
    float h = fmaf(r3, w1r.w, fmaf(r2, w1r.z, fmaf(r1, w1r.y, fmaf(r0, w1r.x, b1f))));
    h = fmaxf(h, 0.f);
    fa[0] = fmaf(h, w2r.x, fa[0]);
    fa[1] = fmaf(h, w2r.y, fa[1]);
    fa[2] = fmaf(h, w2r.z, fa[2]);
    fa[3] = fmaf(h, w2r.w, fa[3]);
  }
  redf[fc][tok][0] = fa[0]; redf[fc][tok][1] = fa[1];
  redf[fc][tok][2] = fa[2]; redf[fc][tok][3] = fa[3];
  __syncthreads();

  if (fc == 0) {
    float t2[4];
#pragma unroll
    for (int c = 0; c < 4; ++c) {
      float s = b2v[c];
#pragma unroll
      for (int k = 0; k < 8; ++k) s += redf[k][tok][c];
      t2[c] = ress[tok][c] + s;
    }
    float y[4];
    ln4(t2, g2, be2, y);
    if (last) {
      outp[gq] = fmaf(y[3], Wfc[3], fmaf(y[2], Wfc[2], fmaf(y[1], Wfc[1], fmaf(y[0], Wfc[0], bfc[0]))));
    } else {
      *(float4*)(Xout + (size_t)gq*4) = make_float4(y[0], y[1], y[2], y[3]);
      float fr[12];
      compute_feat(y, smn, fr);
      float4* fp = (float4*)(feat + (size_t)gq*12);
      fp[0] = ((float4*)fr)[0]; fp[1] = ((float4*)fr)[1]; fp[2] = ((float4*)fr)[2];
    }
  }
}

extern "C" void kernel_launch(void* const* d_in, const int* in_sizes, int n_in,
                              void* d_out, int out_size, void* d_ws, size_t ws_size,
                              hipStream_t stream)
{
  const float* KEY   = (const float*)d_in[0];
  const float* VALUE = (const float*)d_in[1];
  const float* Wq  = (const float*)d_in[2];
  const float* bq  = (const float*)d_in[3];
  const float* Wk  = (const float*)d_in[4];
  const float* bk  = (const float*)d_in[5];
  const float* Wv  = (const float*)d_in[6];
  const float* bv  = (const float*)d_in[7];
  const float* Wo  = (const float*)d_in[8];
  const float* bo  = (const float*)d_in[9];
  const float* bw  = (const float*)d_in[10];
  const float* g1  = (const float*)d_in[11];
  const float* be1 = (const float*)d_in[12];
  const float* W1  = (const float*)d_in[13];
  const float* b1  = (const float*)d_in[14];
  const float* W2  = (const float*)d_in[15];
  const float* b2  = (const float*)d_in[16];
  const float* g2  = (const float*)d_in[17];
  const float* be2 = (const float*)d_in[18];
  const float* Wfc = (const float*)d_in[19];
  const float* bfc = (const float*)d_in[20];
  float* out = (float*)d_out;

  float* w    = (float*)d_ws;
  float* sm   = w;              // 128
  float* w1t  = w + 128;        // 12288
  float* feat = w + 12416;      // 393216
  float* X0   = w + 405632;     // 131072
  float* X1   = w + 536704;     // 131072
  float* part = w + 667776;     // 2097152

  prep_kernel<<<2, 64, 0, stream>>>(Wq, bq, Wk, bk, Wv, bv, Wo, bw, W1, b1, W2, sm, w1t);
  f0_kernel<<<128, 256, 0, stream>>>(KEY, VALUE, sm, X0, feat);

  // layer 0
  attn_kernel<<<512, 256, 0, stream>>>(feat, X0, part);
  combine_kernel<<<512, 512, 0, stream>>>(part, X0, w1t,
      bo, g1, be1, b2, g2, be2,
      sm + 64, X1, feat, Wfc, bfc, out, 0);

  // layer 1
  attn_kernel<<<512, 256, 0, stream>>>(feat, X1, part);
  combine_kernel<<<512, 512, 0, stream>>>(part, X1, w1t + FF*12,
      bo + 4, g1 + 4, be1 + 4, b2 + 4, g2 + 4, be2 + 4,
      sm, X0, feat, Wfc, bfc, out, 1);
}

// Round 4
// 186.770 us; speedup vs baseline: 1.0694x; 1.0269x over previous
//
#include <hip/hip_runtime.h>

#define BB 16
#define SS 2048
#define NTOK (BB*SS)
#define FF 512
#define EPSF 1e-5f

#if __has_builtin(__builtin_amdgcn_exp2f)
#define EXP2F(x) __builtin_amdgcn_exp2f(x)
#else
#define EXP2F(x) exp2f(x)
#endif

// ---------------- ws float layout ----------------
// sm   : [L][64]       fused small mats (exp2-prescaled)   @ 0       (128)
// w1t  : [L][512][12]  {w1col[4], w2row[4], b1, pad3}      @ 128     (12288)
// X0   : [NTOK][4]                                         @ 12416   (131072)
// X1   : [NTOK][4]                                         @ 143488  (131072)
// part : [8][NTOK][8]  per-keyblock partials (padded to 8) @ 274560  (2097152)
// total 2,371,712 floats = 9.5 MB

__device__ __forceinline__ float wred64(float v) {
#pragma unroll
  for (int m = 32; m > 0; m >>= 1) v += __shfl_xor(v, m, 64);
  return v;
}

// sm layout (per layer, stride 64):
// 0:M4[16] (bw2*Wq^T Wk)   16:Bk[16] (-.5 bw2 Wk^T Wk)   32:WVO[16] (Wv*Wo)
// 48:ak[4]  52:bvo[4]  56:ck      where bw2 = bw^2 * log2(e)

// blocks 0..127: build X0 from KEY/VALUE. blocks 128..129: weight prep for layer bid-128.
__global__ __launch_bounds__(256) void prep_kernel(
    const float* __restrict__ KEY, const float* __restrict__ VALUE,
    const float* __restrict__ Wq, const float* __restrict__ bq,
    const float* __restrict__ Wk, const float* __restrict__ bk,
    const float* __restrict__ Wv, const float* __restrict__ bv,
    const float* __restrict__ Wo, const float* __restrict__ bw,
    const float* __restrict__ W1, const float* __restrict__ b1,
    const float* __restrict__ W2,
    float* __restrict__ sm, float* __restrict__ w1t, float* __restrict__ X0)
{
  const int bid = blockIdx.x;
  if (bid < 128) {
    const int gq = bid*256 + threadIdx.x;
    *(float4*)(X0 + (size_t)gq*4) =
        make_float4(KEY[gq*3 + 0], KEY[gq*3 + 1], KEY[gq*3 + 2], VALUE[gq]);
    return;
  }
  const int i = bid - 128;        // layer
  if (threadIdx.x >= 64) return;
  const int lane = threadIdx.x;   // 0..63
  float m4[4][4] = {{0}}, gkk[4][4] = {{0}}, wvo[4][4] = {{0}};
  float akk[4] = {0}, bvo[4] = {0};
  float ck1 = 0.f, ck2 = 0.f;

  for (int h = lane; h < 256; h += 64) {
    float vq[4], vk[4], vv[4], wo4[4];
#pragma unroll
    for (int a = 0; a < 4; ++a) {
      vq[a]  = Wq[(i*4 + a)*256 + h];
      vk[a]  = Wk[(i*4 + a)*256 + h];
      vv[a]  = Wv[(i*4 + a)*256 + h];
      wo4[a] = Wo[(i*256 + h)*4 + a];
    }
    const float bqh = bq[i*256 + h], bkh = bk[i*256 + h], bvh = bv[i*256 + h];
#pragma unroll
    for (int a = 0; a < 4; ++a) {
#pragma unroll
      for (int c = 0; c < 4; ++c) {
        m4[a][c]  = fmaf(vq[a], vk[c], m4[a][c]);
        gkk[a][c] = fmaf(vk[a], vk[c], gkk[a][c]);
        wvo[a][c] = fmaf(vv[a], wo4[c], wvo[a][c]);
      }
      akk[a] = fmaf(vk[a], bqh - bkh, akk[a]);
      bvo[a] = fmaf(bvh, wo4[a], bvo[a]);
    }
    ck1 = fmaf(bqh, bkh, ck1);
    ck2 = fmaf(bkh, bkh, ck2);
  }
#pragma unroll
  for (int a = 0; a < 4; ++a) {
#pragma unroll
    for (int c = 0; c < 4; ++c) {
      m4[a][c]  = wred64(m4[a][c]);
      gkk[a][c] = wred64(gkk[a][c]);
      wvo[a][c] = wred64(wvo[a][c]);
    }
    akk[a] = wred64(akk[a]);
    bvo[a] = wred64(bvo[a]);
  }
  ck1 = wred64(ck1); ck2 = wred64(ck2);

  if (lane == 0) {
    const float bwv = bw[i];
    const float bw2 = bwv * bwv * 1.44269504088896f;   // exp2 prescale
    float* s = sm + i*64;
#pragma unroll
    for (int a = 0; a < 4; ++a) {
#pragma unroll
      for (int c = 0; c < 4; ++c) {
        s[a*4+c]      = bw2 * m4[a][c];
        s[16 + a*4+c] = -0.5f * bw2 * gkk[a][c];
        s[32 + a*4+c] = wvo[a][c];
      }
      s[48+a] = bw2 * akk[a];
      s[52+a] = bvo[a];
    }
    s[56] = bw2 * (ck1 - 0.5f * ck2);
  }
  // FFN weight repack: w1t[f] = {W1[:,f], W2[f,:], b1[f], pad}
  for (int f = lane; f < FF; f += 64) {
    float* rec = w1t + (i*FF + f)*12;
#pragma unroll
    for (int c = 0; c < 4; ++c) rec[c]   = W1[(i*4 + c)*FF + f];
#pragma unroll
    for (int c = 0; c < 4; ++c) rec[4+c] = W2[(i*FF + f)*4 + c];
    rec[8] = b1[i*FF + f];
    rec[9] = 0.f; rec[10] = 0.f; rec[11] = 0.f;
  }
}

// feat record: {P[4], VT[4], R}; query-side constant dropped (cancels in softmax)
__device__ __forceinline__ void compute_feat(const float x[4], const float* __restrict__ s,
                                             float* __restrict__ featrec)
{
  float P[4], VT[4], tk[4];
#pragma unroll
  for (int a = 0; a < 4; ++a) {
    P[a]  = fmaf(s[a*4+3], x[3], fmaf(s[a*4+2], x[2], fmaf(s[a*4+1], x[1], s[a*4+0]*x[0])));
    tk[a] = fmaf(s[16+a*4+3], x[3], fmaf(s[16+a*4+2], x[2], fmaf(s[16+a*4+1], x[1], s[16+a*4+0]*x[0])));
    VT[a] = s[52+a] + fmaf(s[32+3*4+a], x[3], fmaf(s[32+2*4+a], x[2], fmaf(s[32+1*4+a], x[1], s[32+0*4+a]*x[0])));
  }
  float R = s[56];
#pragma unroll
  for (int a = 0; a < 4; ++a) R = fmaf(tk[a] + s[48+a], x[a], R);
  float4* fp = (float4*)featrec;
  fp[0] = make_float4(P[0], P[1], P[2], P[3]);
  fp[1] = make_float4(VT[0], VT[1], VT[2], VT[3]);
  fp[2] = make_float4(R, 0.f, 0.f, 0.f);
}

// attention partials: block covers 512 queries x 256 keys.
// Key features computed on the fly from X during LDS staging (no feat array).
// 4 waves share the 512 queries (8 q/lane); each wave owns 64 of the 256 staged keys.
// Cross-wave LDS reduction (stride 21, gcd(21,32)=1 -> 2-way aliasing, free).
__global__ __launch_bounds__(256) void attn_kernel(
    const float* __restrict__ X, const float* __restrict__ sm,
    float* __restrict__ part)
{
  __shared__ float smem[512*21];    // 43 KB; first 3072 floats double as key buffer
  const int bid = blockIdx.x;
  const int b = bid >> 5;
  const int r = bid & 31;
  const int qg = r >> 3, kb = r & 7;
  const int qbase = (b << 11) + (qg << 9);
  const int kbase = (b << 11) + (kb << 8);
  const int tid = threadIdx.x;
  const int lane = tid & 63, wave = tid >> 6;

  // stage 256 key-feature records, computed from X
  {
    const float4 xk = *(const float4*)(X + (size_t)(kbase + tid)*4);
    float xr[4] = {xk.x, xk.y, xk.z, xk.w};
    float fr[12];
    compute_feat(xr, sm, fr);
    float* dst = smem + tid*12;
    ((float4*)dst)[0] = ((float4*)fr)[0];
    ((float4*)dst)[1] = ((float4*)fr)[1];
    dst[8] = fr[8];
  }

  float xq[8][4], acc[8][5];
#pragma unroll
  for (int j = 0; j < 8; ++j) {
    const float4 xv = *(const float4*)(X + (size_t)(qbase + j*64 + lane)*4);
    xq[j][0] = xv.x; xq[j][1] = xv.y; xq[j][2] = xv.z; xq[j][3] = xv.w;
#pragma unroll
    for (int c = 0; c < 5; ++c) acc[j][c] = 0.f;
  }
  __syncthreads();

  const float* kf = smem + wave*64*12;
#pragma unroll 2
  for (int k = 0; k < 64; ++k) {
    const float* kp = kf + k*12;
    const float4 P  = *(const float4*)kp;
    const float4 VT = *(const float4*)(kp + 4);
    const float R = kp[8];
#pragma unroll
    for (int j = 0; j < 8; ++j) {
      float l = fmaf(xq[j][3], P.w, fmaf(xq[j][2], P.z,
                fmaf(xq[j][1], P.y, fmaf(xq[j][0], P.x, R))));
      const float e = EXP2F(l);
      acc[j][0] = fmaf(e, VT.x, acc[j][0]);
      acc[j][1] = fmaf(e, VT.y, acc[j][1]);
      acc[j][2] = fmaf(e, VT.z, acc[j][2]);
      acc[j][3] = fmaf(e, VT.w, acc[j][3]);
      acc[j][4] += e;
    }
  }
  __syncthreads();     // key buffer dead; reuse LDS for cross-wave reduction
#pragma unroll
  for (int j = 0; j < 8; ++j) {
    float* rr = smem + (j*64 + lane)*21 + wave*5;
    rr[0] = acc[j][0]; rr[1] = acc[j][1]; rr[2] = acc[j][2];
    rr[3] = acc[j][3]; rr[4] = acc[j][4];
  }
  __syncthreads();
  float* pb = part + (size_t)kb * NTOK * 8;
#pragma unroll
  for (int t = 0; t < 2; ++t) {
    const int q = t*256 + tid;
    const float* rr = smem + q*21;
    float s0 = 0.f, s1 = 0.f, s2 = 0.f, s3 = 0.f, s4 = 0.f;
#pragma unroll
    for (int w = 0; w < 4; ++w) {
      s0 += rr[w*5+0]; s1 += rr[w*5+1]; s2 += rr[w*5+2];
      s3 += rr[w*5+3]; s4 += rr[w*5+4];
    }
    float* pp = pb + (size_t)(qbase + q)*8;
    *(float4*)pp = make_float4(s0, s1, s2, s3);
    pp[4] = s4;
  }
}

__device__ __forceinline__ void ln4(const float t[4], const float* __restrict__ g,
                                    const float* __restrict__ b, float r[4])
{
  const float m = 0.25f*(t[0]+t[1]+t[2]+t[3]);
  const float d0 = t[0]-m, d1 = t[1]-m, d2 = t[2]-m, d3 = t[3]-m;
  const float v = 0.25f*(d0*d0 + d1*d1 + d2*d2 + d3*d3);
  const float sc = rsqrtf(v + EPSF);
  r[0] = fmaf(d0*sc, g[0], b[0]);
  r[1] = fmaf(d1*sc, g[1], b[1]);
  r[2] = fmaf(d2*sc, g[2], b[2]);
  r[3] = fmaf(d3*sc, g[3], b[3]);
}

// combine: block = 512 thr = 64 tokens x 8 F-chunks; fc k reduces part stripe k
__global__ __launch_bounds__(512) void combine_kernel(
    const float* __restrict__ part, const float* __restrict__ Xin,
    const float* __restrict__ w1t,
    const float* __restrict__ bo, const float* __restrict__ g1, const float* __restrict__ be1,
    const float* __restrict__ b2v, const float* __restrict__ g2, const float* __restrict__ be2,
    float* __restrict__ Xout,
    const float* __restrict__ Wfc, const float* __restrict__ bfc,
    float* __restrict__ outp, int last)
{
  const int tok = threadIdx.x & 63, fc = threadIdx.x >> 6;
  const int gq = blockIdx.x*64 + tok;
  __shared__ float redp[8][64][5];
  __shared__ float ress[64][4];
  __shared__ float redf[8][64][4];

  {
    const float* pp = part + ((size_t)fc*NTOK + gq)*8;
    const float4 v = *(const float4*)pp;
    redp[fc][tok][0] = v.x; redp[fc][tok][1] = v.y;
    redp[fc][tok][2] = v.z; redp[fc][tok][3] = v.w;
    redp[fc][tok][4] = pp[4];
  }
  __syncthreads();

  if (fc == 0) {
    float acc[5] = {0,0,0,0,0};
#pragma unroll
    for (int k = 0; k < 8; ++k)
#pragma unroll
      for (int c = 0; c < 5; ++c) acc[c] += redp[k][tok][c];
    const float inv = 1.0f / acc[4];
    const float4 xv = *(const float4*)(Xin + (size_t)gq*4);
    float t[4];
    t[0] = xv.x + fmaf(acc[0], inv, bo[0]);
    t[1] = xv.y + fmaf(acc[1], inv, bo[1]);
    t[2] = xv.z + fmaf(acc[2], inv, bo[2]);
    t[3] = xv.w + fmaf(acc[3], inv, bo[3]);
    float r[4];
    ln4(t, g1, be1, r);
    ress[tok][0] = r[0]; ress[tok][1] = r[1]; ress[tok][2] = r[2]; ress[tok][3] = r[3];
  }
  __syncthreads();

  const float r0 = ress[tok][0], r1 = ress[tok][1], r2 = ress[tok][2], r3 = ress[tok][3];
  float fa[4] = {0,0,0,0};
  const float* wt = w1t + (size_t)fc*64*12;
#pragma unroll 4
  for (int f = 0; f < 64; ++f) {
    const float* rec = wt + f*12;
    const float4 w1r = *(const float4*)rec;
    const float4 w2r = *(const float4*)(rec + 4);
    const float b1f = rec[8];
    float h = fmaf(r3, w1r.w, fmaf(r2, w1r.z, fmaf(r1, w1r.y, fmaf(r0, w1r.x, b1f))));
    h = fmaxf(h, 0.f);
    fa[0] = fmaf(h, w2r.x, fa[0]);
    fa[1] = fmaf(h, w2r.y, fa[1]);
    fa[2] = fmaf(h, w2r.z, fa[2]);
    fa[3] = fmaf(h, w2r.w, fa[3]);
  }
  redf[fc][tok][0] = fa[0]; redf[fc][tok][1] = fa[1];
  redf[fc][tok][2] = fa[2]; redf[fc][tok][3] = fa[3];
  __syncthreads();

  if (fc == 0) {
    float t2[4];
#pragma unroll
    for (int c = 0; c < 4; ++c) {
      float s = b2v[c];
#pragma unroll
      for (int k = 0; k < 8; ++k) s += redf[k][tok][c];
      t2[c] = ress[tok][c] + s;
    }
    float y[4];
    ln4(t2, g2, be2, y);
    if (last) {
      outp[gq] = fmaf(y[3], Wfc[3], fmaf(y[2], Wfc[2], fmaf(y[1], Wfc[1], fmaf(y[0], Wfc[0], bfc[0]))));
    } else {
      *(float4*)(Xout + (size_t)gq*4) = make_float4(y[0], y[1], y[2], y[3]);
    }
  }
}

extern "C" void kernel_launch(void* const* d_in, const int* in_sizes, int n_in,
                              void* d_out, int out_size, void* d_ws, size_t ws_size,
                              hipStream_t stream)
{
  const float* KEY   = (const float*)d_in[0];
  const float* VALUE = (const float*)d_in[1];
  const float* Wq  = (const float*)d_in[2];
  const float* bq  = (const float*)d_in[3];
  const float* Wk  = (const float*)d_in[4];
  const float* bk  = (const float*)d_in[5];
  const float* Wv  = (const float*)d_in[6];
  const float* bv  = (const float*)d_in[7];
  const float* Wo  = (const float*)d_in[8];
  const float* bo  = (const float*)d_in[9];
  const float* bw  = (const float*)d_in[10];
  const float* g1  = (const float*)d_in[11];
  const float* be1 = (const float*)d_in[12];
  const float* W1  = (const float*)d_in[13];
  const float* b1  = (const float*)d_in[14];
  const float* W2  = (const float*)d_in[15];
  const float* b2  = (const float*)d_in[16];
  const float* g2  = (const float*)d_in[17];
  const float* be2 = (const float*)d_in[18];
  const float* Wfc = (const float*)d_in[19];
  const float* bfc = (const float*)d_in[20];
  float* out = (float*)d_out;

  float* w    = (float*)d_ws;
  float* sm   = w;              // 128
  float* w1t  = w + 128;        // 12288
  float* X0   = w + 12416;      // 131072
  float* X1   = w + 143488;     // 131072
  float* part = w + 274560;     // 2097152

  prep_kernel<<<130, 256, 0, stream>>>(KEY, VALUE, Wq, bq, Wk, bk, Wv, bv, Wo, bw,
                                       W1, b1, W2, sm, w1t, X0);

  // layer 0
  attn_kernel<<<512, 256, 0, stream>>>(X0, sm, part);
  combine_kernel<<<512, 512, 0, stream>>>(part, X0, w1t,
      bo, g1, be1, b2, g2, be2,
      X1, Wfc, bfc, out, 0);

  // layer 1
  attn_kernel<<<512, 256, 0, stream>>>(X1, sm + 64, part);
  combine_kernel<<<512, 512, 0, stream>>>(part, X1, w1t + FF*12,
      bo + 4, g1 + 4, be1 + 4, b2 + 4, g2 + 4, be2 + 4,
      X0, Wfc, bfc, out, 1);
}